// Round 23
// baseline (156.957 us; speedup 1.0000x reference)
//
#include <hip/hip_runtime.h>

#define BBATCH 1024
#define NPAIR 512
#define PP 23      // nodes per frame
#define FF 14
#define DD 256
#define CC 23

#define SLSTR 264           // sl/sro row stride (f16 halves)
// h lives permanently in MFMA A-frag layout (f16): [3 mt][8 ks][64 lane][8 e]
#define FRAG_OFF  0                    // 12288 f16 = 24576 B, persistent
#define SL_OFF    24576                // [23][264] f16 = 12144 B
#define SRO_OFF   (SL_OFF + 12144)     // [23][264] f16
#define ALPHA_OFF (SRO_OFF + 12144)    // [4h][2mt][512] f16 = 8192 B
#define XS_OFF    (ALPHA_OFF)          // [46][14] f32 (in_proj only, overlaps aF)
#define SMEM_SZ   (ALPHA_OFF + 8192)   // 57056 B -> 2 blocks/CU

// head-phase LDS (reuses aF region, dead after last aggregate)
#define GV_OFF    (ALPHA_OFF)          // gvals [2][256] f32
#define T1_OFF    (ALPHA_OFF + 2048)
#define GT_OFF    (ALPHA_OFF + 4096)
#define LG_OFF    (ALPHA_OFF + 6144)
#define PRB_OFF   (ALPHA_OFF + 6400)
#define RED_OFF   (ALPHA_OFF + 6656)

// involutive 16B-block swizzle within a sl/sro row (blocks of 8 halves)
#define SWZB(b) ((b) ^ (((b) >> 3) & 7))
#define SWZC(c) (SWZB((c) >> 3) * 8 + ((c) & 7))

typedef _Float16 f16;
typedef __attribute__((ext_vector_type(8))) _Float16 f16x8;
typedef __attribute__((ext_vector_type(4))) _Float16 f16x4;
typedef __attribute__((ext_vector_type(2))) _Float16 f16x2;
typedef __attribute__((ext_vector_type(4))) float f32x4;

__device__ __forceinline__ int frag_off(int r, int c) {
    return ((r >> 4) * 8 + (c >> 5)) * 512 +
           ((r & 15) + (((c & 31) >> 3) << 4)) * 8 + (c & 7);
}

// ---------------- weight prep (blocks 0..95) + EB (blocks 96..118) ----------------
__global__ __launch_bounds__(256) void k_prep(const float* __restrict__ Wl,
    const float* __restrict__ Wr, const float* __restrict__ E,
    const float* __restrict__ Ws1, f16* __restrict__ Bf, float* __restrict__ EB)
{
    __shared__ float ws[DD][16];
    int t = threadIdx.x;
    if (blockIdx.x < 96) {
        int bid = blockIdx.x;            // l*32 + ntile
        int ll = bid >> 5, ntile = bid & 31;
        int n0 = ntile * 16;
        const float* W = (n0 < 256) ? (Wl + (size_t)ll * 65536) : (Wr + (size_t)ll * 65536);
        int c0 = n0 & 255;
        for (int kk = t >> 4; kk < DD; kk += 16)
            ws[kk][t & 15] = W[(size_t)kk * 256 + c0 + (t & 15)];
        __syncthreads();
        size_t base = (size_t)bid * 4096;
        for (int idx = t; idx < 4096; idx += 256) {
            int ks = idx >> 9;
            int lane = (idx >> 3) & 63;
            int e = idx & 7;
            int col = lane & 15;
            int k = ks * 32 + ((lane >> 4) << 3) + e;
            Bf[base + idx] = (f16)ws[k][col];
        }
    } else {
        int c = blockIdx.x - 96;
        float acc = 0.f;
        for (int k = 0; k < DD; ++k)
            acc = fmaf(E[c * DD + k], Ws1[(DD + k) * DD + t], acc);
        EB[c * DD + t] = acc;
    }
}

// ---------------- fully fused: in_proj + 3 GATv2 layers + readout + head ----------------
__global__ __launch_bounds__(512, 4) void k_fused(
    const float* __restrict__ x, const float* __restrict__ Win,
    const float* __restrict__ bin, const f16* __restrict__ Bf,
    const float* __restrict__ att,
    const float* __restrict__ Wr1, const float* __restrict__ br1,
    const float* __restrict__ Wr2, const float* __restrict__ br2,
    const float* __restrict__ Ws1, const float* __restrict__ bs1,
    const float* __restrict__ Ws2, const float* __restrict__ bs2,
    const float* __restrict__ EB, float* __restrict__ out)
{
    __shared__ __align__(16) char smem[SMEM_SZ];
    f16* frag   = (f16*)(smem + FRAG_OFF);     // h, persistent, A-frag layout
    f16* sl16   = (f16*)(smem + SL_OFF);
    f16* sro16  = (f16*)(smem + SRO_OFF);
    f16* aF     = (f16*)(smem + ALPHA_OFF);    // final alphas in MFMA A-frag layout
    float* xs   = (float*)(smem + XS_OFF);
    float* gv   = (float*)(smem + GV_OFF);     // head: g values [2][256]
    float* t1s  = (float*)(smem + T1_OFF);
    float* gts  = (float*)(smem + GT_OFF);
    float* lgs  = (float*)(smem + LG_OFF);
    float* prb  = (float*)(smem + PRB_OFF);
    float* red  = (float*)(smem + RED_OFF);

    int t = threadIdx.x;
    int pair = blockIdx.x;

    // ---- stage x ----
    for (int idx = t; idx < 46 * FF; idx += 512)
        xs[idx] = x[(size_t)pair * 46 * FF + idx];
    __syncthreads();

    // ---- in_proj: h -> frag f16 (pad rows 46,47 zeroed) ----
    {
        int c2 = (t & 127) * 2, rp = t >> 7;   // rp 0..3
        float2 bb = *(const float2*)&bin[c2];
        for (int r = rp; r < 48; r += 4) {
            float h0 = 0.f, h1 = 0.f;
            if (r < 46) {
                h0 = bb.x; h1 = bb.y;
#pragma unroll
                for (int f = 0; f < FF; ++f) {
                    float xv = xs[r * FF + f];
                    float2 wv = *(const float2*)&Win[f * DD + c2];  // L1-hot
                    h0 = fmaf(xv, wv.x, h0);
                    h1 = fmaf(xv, wv.y, h1);
                }
            }
            f16x2 hv2 = { (f16)h0, (f16)h1 };
            *(f16x2*)(frag + frag_off(r, c2)) = hv2;
        }
    }

    int ln = t & 63, w = t >> 6;   // 8 waves

    // score mapping: t = i*16 + ch  (368 active)
    int sc_i  = t >> 4;
    int sc_ch = t & 15;
    int sc_hh = sc_ch >> 2;
    bool sc_act = (t < 368);
    int sb0 = SWZB(2 * sc_ch) * 8;
    int sb1 = SWZB(2 * sc_ch + 1) * 8;

    for (int layer = 0; layer < 3; ++layer) {
        __syncthreads();   // frag ready (in_proj or previous aggregate)

        // one-time zero of alphaF (K-pad slots stay zero forever); xs dead now
        if (layer == 0)
            *(f32x4*)(smem + ALPHA_OFF + t * 16) = (f32x4)0.f;

        // ---- GEMM: single-term f16; M=48(2 pad rows), 8 waves x 4 ntiles ----
        const f16* pB = Bf + (size_t)layer * 131072 + (size_t)(w * 4) * 4096 + ln * 8;
        const f16* lA = frag + ln * 8;

        f32x4 acc[3][4];
#pragma unroll
        for (int mt = 0; mt < 3; ++mt)
#pragma unroll
            for (int nt = 0; nt < 4; ++nt) acc[mt][nt] = (f32x4)0.0f;

        __builtin_amdgcn_s_setprio(1);
#pragma unroll
        for (int ks = 0; ks < 8; ++ks) {
            f16x8 a0 = *(const f16x8*)(lA + (0 * 8 + ks) * 512);
            f16x8 a1 = *(const f16x8*)(lA + (1 * 8 + ks) * 512);
            f16x8 a2 = *(const f16x8*)(lA + (2 * 8 + ks) * 512);
#pragma unroll
            for (int nt = 0; nt < 4; ++nt) {
                f16x8 b = *(const f16x8*)(pB + (nt * 8 + ks) * 512);
                acc[0][nt] = __builtin_amdgcn_mfma_f32_16x16x32_f16(a0, b, acc[0][nt], 0, 0, 0);
                acc[1][nt] = __builtin_amdgcn_mfma_f32_16x16x32_f16(a1, b, acc[1][nt], 0, 0, 0);
                acc[2][nt] = __builtin_amdgcn_mfma_f32_16x16x32_f16(a2, b, acc[2][nt], 0, 0, 0);
            }
        }
        __builtin_amdgcn_s_setprio(0);
        __syncthreads();   // frag reads done for this layer; sl/sro writable

        // ---- per-frame attention ----
        for (int f = 0; f < 2; ++f) {
            // scatter acc -> swizzled f16 sl/sro
#pragma unroll
            for (int mt = 0; mt < 3; ++mt) {
                int rbase = mt * 16 + (ln >> 4) * 4;
#pragma unroll
                for (int nt = 0; nt < 4; ++nt) {
                    int col = w * 64 + nt * 16 + (ln & 15);
                    f16* dst = (col < 256) ? sl16 : sro16;
                    int cc = col & 255;
                    int sc = SWZC(cc);
#pragma unroll
                    for (int r2 = 0; r2 < 4; ++r2) {
                        int i = rbase + r2 - f * PP;
                        if (0 <= i && i < PP) dst[i * SLSTR + sc] = (f16)acc[mt][nt][r2];
                    }
                }
            }
            __syncthreads();

            // scores + inline parallel softmax: all 23 p's kept in registers
            // (after the quad butterfly every lane holds the full p_j);
            // tree-max + independent exps, then quad-split final-alpha write.
            if (sc_act) {
                const float* ap = att + layer * DD + sc_ch * 16;
                float4 af0 = *(const float4*)(ap);
                float4 af1 = *(const float4*)(ap + 4);
                float4 af2 = *(const float4*)(ap + 8);
                float4 af3 = *(const float4*)(ap + 12);
                f16x8 av0 = { (f16)af0.x, (f16)af0.y, (f16)af0.z, (f16)af0.w,
                              (f16)af1.x, (f16)af1.y, (f16)af1.z, (f16)af1.w };
                f16x8 av1 = { (f16)af2.x, (f16)af2.y, (f16)af2.z, (f16)af2.w,
                              (f16)af3.x, (f16)af3.y, (f16)af3.z, (f16)af3.w };
                const f16* srp = sro16 + sc_i * SLSTR;
                f16x8 rv0 = *(const f16x8*)(srp + sb0);
                f16x8 rv1 = *(const f16x8*)(srp + sb1);
                float p[PP];
#pragma unroll
                for (int j = 0; j < PP; ++j) {
                    const f16* slp = sl16 + j * SLSTR;
                    f16x8 v0 = *(const f16x8*)(slp + sb0) + rv0;
                    f16x8 v1 = *(const f16x8*)(slp + sb1) + rv1;
                    v0 = __builtin_elementwise_max(v0, v0 * (f16)0.2f);
                    v1 = __builtin_elementwise_max(v1, v1 * (f16)0.2f);
                    f16x8 tot = av0 * v0;
                    tot += av1 * v1;
                    f16x4 t4 = __builtin_shufflevector(tot, tot, 0, 1, 2, 3) +
                               __builtin_shufflevector(tot, tot, 4, 5, 6, 7);
                    float pv = (float)t4[0] + (float)t4[1] + (float)t4[2] + (float)t4[3];
                    pv += __shfl_xor(pv, 1, 64);
                    pv += __shfl_xor(pv, 2, 64);
                    // match f16 storage rounding of the previous path
                    p[j] = (j == sc_i) ? -1e30f : (float)(f16)pv;
                }
                // tree max (independent)
                float m = p[0];
#pragma unroll
                for (int j = 1; j < PP; ++j) m = fmaxf(m, p[j]);
                // exps + sum (independent)
                float s = 0.f;
#pragma unroll
                for (int j = 0; j < PP; ++j) {
                    p[j] = __expf(p[j] - m);
                    // round to f16 as stored, sum what MFMA will sum
                    p[j] = (float)(f16)p[j];
                    s += p[j];
                }
                float inv = 1.f / s;
                int wbase = ((sc_hh * 2 + (sc_i >> 4)) << 9) + ((sc_i & 15) << 3);
                int q = t & 3;
#pragma unroll
                for (int j = 0; j < PP; ++j) {
                    if ((j & 3) == q)
                        aF[wbase + ((j >> 3) << 7) + (j & 7)] = (f16)(p[j] * inv);
                }
            }
            __syncthreads();

            // aggregate via MFMA: wave w -> (head h, mtile mt); h_new -> frag (in place)
            {
                int h = w >> 1, mt = w & 1;
                f16x8 afrag = *(const f16x8*)(aF + ((h * 2 + mt) << 9) + ln * 8);
                int k0 = (ln >> 4) * 8;
                int cb = h * 64 + (ln & 15);
                __builtin_amdgcn_s_setprio(1);
#pragma unroll
                for (int nt = 0; nt < 4; ++nt) {
                    int c = cb + nt * 16;
                    int scn = SWZC(c);
                    f16x8 bfrag;
#pragma unroll
                    for (int e = 0; e < 8; ++e)
                        bfrag[e] = sl16[(k0 + e) * SLSTR + scn];
                    f32x4 a4 = __builtin_amdgcn_mfma_f32_16x16x32_f16(
                        afrag, bfrag, (f32x4)0.0f, 0, 0, 0);
#pragma unroll
                    for (int r2 = 0; r2 < 4; ++r2) {
                        int i = mt * 16 + (ln >> 4) * 4 + r2;
                        if (i < PP) {
                            int fo = frag_off(f * PP + i, c);
                            float res = a4[r2] + (float)frag[fo];
                            frag[fo] = (f16)((res > 0.f) ? res : (__expf(res) - 1.f));
                        }
                    }
                }
                __builtin_amdgcn_s_setprio(0);
            }
            __syncthreads();
        }
    }

    // ---- readout into LDS (aF region now dead) ----
    {
        int f = t >> 8, c = t & 255;
        float s = 0.f;
#pragma unroll
        for (int i = 0; i < PP; ++i) s += (float)frag[frag_off(f * PP + i, c)];
        gv[f * 256 + c] = s * (1.0f / 23.0f);
    }
    __syncthreads();

    // ---- head phase A: t1 = relu(g@Wr1+br1), gtop = g@Ws1[:256]+bs1 ----
    {
        int gg = t >> 8, c = t & 255;
        const float* gp = gv + gg * 256;
        float a1 = 0.f, a2 = 0.f;
        for (int k = 0; k < DD; k += 2) {
            float g0 = gp[k], g1 = gp[k + 1];
            a1 = fmaf(g0, Wr1[k * DD + c], a1);
            a1 = fmaf(g1, Wr1[(k + 1) * DD + c], a1);
            a2 = fmaf(g0, Ws1[k * DD + c], a2);
            a2 = fmaf(g1, Ws1[(k + 1) * DD + c], a2);
        }
        t1s[gg * 256 + c] = fmaxf(a1 + br1[c], 0.f);
        gts[gg * 256 + c] = a2 + bs1[c];
    }
    __syncthreads();

    // ---- head phase B: logits ----
    if (t < 2 * CC) {
        int gg = t / CC, c = t - gg * CC;
        float acc = br2[c];
        const float* tp = t1s + gg * 256;
        for (int d = 0; d < DD; ++d) acc = fmaf(tp[d], Wr2[d * CC + c], acc);
        lgs[gg * CC + c] = acc;
    }
    __syncthreads();

    // ---- head phase C: recv softmax ----
    if (t < 2 * CC) {
        int gg = t / CC, c = t - gg * CC;
        const float* lp = lgs + gg * CC;
        float m = -1e30f;
        for (int cc = 0; cc < CC; ++cc) m = fmaxf(m, lp[cc]);
        float s = 0.f;
        for (int cc = 0; cc < CC; ++cc) s += __expf(lp[cc] - m);
        prb[gg * CC + c] = __expf(lp[c] - m) / s;
    }
    __syncthreads();

    // ---- head phase D: marginalized shot logit ----
    {
        int gg = t >> 8, c = t & 255;
        float gt = gts[gg * 256 + c];
        const float* pp = prb + gg * CC;
        float acc = 0.f;
#pragma unroll
        for (int cls = 0; cls < CC; ++cls)
            acc = fmaf(pp[cls], fmaxf(gt + EB[cls * DD + c], 0.f), acc);
        acc *= Ws2[c];
#pragma unroll
        for (int off = 32; off > 0; off >>= 1) acc += __shfl_down(acc, off, 64);
        if (ln == 0) red[w] = acc;
    }
    __syncthreads();
    if (t < 2)
        out[pair * 2 + t] = red[t * 4] + red[t * 4 + 1] + red[t * 4 + 2] +
                            red[t * 4 + 3] + bs2[0];
}

extern "C" void kernel_launch(void* const* d_in, const int* in_sizes, int n_in,
                              void* d_out, int out_size, void* d_ws, size_t ws_size,
                              hipStream_t stream)
{
    const float* x     = (const float*)d_in[0];
    const float* Win   = (const float*)d_in[3];
    const float* bin   = (const float*)d_in[4];
    const float* Wl    = (const float*)d_in[5];
    const float* Wr    = (const float*)d_in[6];
    const float* att   = (const float*)d_in[7];
    const float* Wr1   = (const float*)d_in[8];
    const float* br1   = (const float*)d_in[9];
    const float* Wr2   = (const float*)d_in[10];
    const float* br2   = (const float*)d_in[11];
    const float* Erecv = (const float*)d_in[12];
    const float* Ws1   = (const float*)d_in[13];
    const float* bs1   = (const float*)d_in[14];
    const float* Ws2   = (const float*)d_in[15];
    const float* bs2   = (const float*)d_in[16];
    float* out = (float*)d_out;

    f16* Bf   = (f16*)d_ws;                          // [3][32][4096] f16
    float* EB = (float*)(Bf + (size_t)3 * 131072);   // [CC][DD]

    k_prep<<<dim3(96 + CC), dim3(256), 0, stream>>>(Wl, Wr, Erecv, Ws1, Bf, EB);
    k_fused<<<dim3(NPAIR), dim3(512), 0, stream>>>(x, Win, bin, Bf, att,
        Wr1, br1, Wr2, br2, Ws1, bs1, Ws2, bs2, EB, out);
}

// Round 24
// 145.586 us; speedup vs baseline: 1.0781x; 1.0781x over previous
//
#include <hip/hip_runtime.h>

#define BBATCH 1024
#define NPAIR 512
#define PP 23      // nodes per frame
#define FF 14
#define DD 256
#define CC 23

#define HSTR 258            // hstate row stride (f32 words)
#define SLSTR 264           // sl/sro row stride (f16 halves)
#define RG 47472            // hstate bytes (46*258*4)
#define SL_OFF    (RG)                // [23][264] f16 = 12144 B
#define SRO_OFF   (RG + 12144)        // [23][264] f16
#define FRAG_OFF  (RG)                // 12288 f16 = 24576 B (GEMM phase, overlaps sl/sro)
#define ALPHA_OFF (RG + 24576)        // [4h][2mt][512] f16 = 8192 B (scores/alphas, frag layout)
#define XS_OFF    (ALPHA_OFF)         // [46][14] f32 (in_proj only)
#define INVZ_OFF  (ALPHA_OFF + 8192)  // [23][4] f32 = 368 B (softmax 1/Z)
#define SMEM_SZ   (INVZ_OFF + 384)    // 80624 B -> 2 blocks/CU (<= 81920)

// head-phase LDS (reuses aF region, dead after last aggregate)
#define GV_OFF    (ALPHA_OFF)          // gvals [2][256] f32 = 2048
#define T1_OFF    (ALPHA_OFF + 2048)   // t1    [2][256] f32 = 2048
#define GT_OFF    (ALPHA_OFF + 4096)   // gtop  [2][256] f32 = 2048
#define LG_OFF    (ALPHA_OFF + 6144)   // logits[2][23]  f32 = 184
#define PRB_OFF   (ALPHA_OFF + 6400)   // probs [2][23]  f32 = 184
#define RED_OFF   (ALPHA_OFF + 6656)   // red   [8]      f32

// involutive 16B-block swizzle within a sl/sro row (blocks of 8 halves)
#define SWZB(b) ((b) ^ (((b) >> 3) & 7))
#define SWZC(c) (SWZB((c) >> 3) * 8 + ((c) & 7))

typedef _Float16 f16;
typedef __attribute__((ext_vector_type(8))) _Float16 f16x8;
typedef __attribute__((ext_vector_type(4))) _Float16 f16x4;
typedef __attribute__((ext_vector_type(2))) _Float16 f16x2;
typedef __attribute__((ext_vector_type(4))) float f32x4;

// ---------------- weight prep (blocks 0..95) + EB (blocks 96..118) ----------------
__global__ __launch_bounds__(256) void k_prep(const float* __restrict__ Wl,
    const float* __restrict__ Wr, const float* __restrict__ E,
    const float* __restrict__ Ws1, f16* __restrict__ Bf, float* __restrict__ EB)
{
    __shared__ float ws[DD][16];
    int t = threadIdx.x;
    if (blockIdx.x < 96) {
        int bid = blockIdx.x;            // l*32 + ntile
        int ll = bid >> 5, ntile = bid & 31;
        int n0 = ntile * 16;
        const float* W = (n0 < 256) ? (Wl + (size_t)ll * 65536) : (Wr + (size_t)ll * 65536);
        int c0 = n0 & 255;
        for (int kk = t >> 4; kk < DD; kk += 16)
            ws[kk][t & 15] = W[(size_t)kk * 256 + c0 + (t & 15)];
        __syncthreads();
        size_t base = (size_t)bid * 4096;
        for (int idx = t; idx < 4096; idx += 256) {
            int ks = idx >> 9;
            int lane = (idx >> 3) & 63;
            int e = idx & 7;
            int col = lane & 15;
            int k = ks * 32 + ((lane >> 4) << 3) + e;
            Bf[base + idx] = (f16)ws[k][col];
        }
    } else {
        int c = blockIdx.x - 96;
        float acc = 0.f;
        for (int k = 0; k < DD; ++k)
            acc = fmaf(E[c * DD + k], Ws1[(DD + k) * DD + t], acc);
        EB[c * DD + t] = acc;
    }
}

// ---------------- fully fused: in_proj + 3 GATv2 layers + readout + head ----------------
__global__ __launch_bounds__(512, 4) void k_fused(
    const float* __restrict__ x, const float* __restrict__ Win,
    const float* __restrict__ bin, const f16* __restrict__ Bf,
    const float* __restrict__ att,
    const float* __restrict__ Wr1, const float* __restrict__ br1,
    const float* __restrict__ Wr2, const float* __restrict__ br2,
    const float* __restrict__ Ws1, const float* __restrict__ bs1,
    const float* __restrict__ Ws2, const float* __restrict__ bs2,
    const float* __restrict__ EB, float* __restrict__ out)
{
    __shared__ __align__(16) char smem[SMEM_SZ];
    float* hstate = (float*)smem;              // [46][258] f32, persistent
    f16* sl16   = (f16*)(smem + SL_OFF);
    f16* sro16  = (f16*)(smem + SRO_OFF);
    f16* frag   = (f16*)(smem + FRAG_OFF);     // packed A fragments (GEMM phase)
    f16* aF     = (f16*)(smem + ALPHA_OFF);    // scores/alphas in MFMA A-frag layout
    float* xs   = (float*)(smem + XS_OFF);
    float* invZ = (float*)(smem + INVZ_OFF);   // [23][4]
    float* gv   = (float*)(smem + GV_OFF);     // head: g values [2][256]
    float* t1s  = (float*)(smem + T1_OFF);
    float* gts  = (float*)(smem + GT_OFF);
    float* lgs  = (float*)(smem + LG_OFF);
    float* prb  = (float*)(smem + PRB_OFF);
    float* red  = (float*)(smem + RED_OFF);

    int t = threadIdx.x;
    int pair = blockIdx.x;

    // ---- stage x ----
    for (int idx = t; idx < 46 * FF; idx += 512)
        xs[idx] = x[(size_t)pair * 46 * FF + idx];
    __syncthreads();

    // ---- in_proj: hstate f32 + frag f16 ----
    {
        int c2 = (t & 127) * 2, rp = t >> 7;   // rp 0..3
        float2 bb = *(const float2*)&bin[c2];
        for (int r = rp; r < 48; r += 4) {
            float h0 = 0.f, h1 = 0.f;
            if (r < 46) {
                h0 = bb.x; h1 = bb.y;
#pragma unroll
                for (int f = 0; f < FF; ++f) {
                    float xv = xs[r * FF + f];
                    float2 wv = *(const float2*)&Win[f * DD + c2];  // L1-hot
                    h0 = fmaf(xv, wv.x, h0);
                    h1 = fmaf(xv, wv.y, h1);
                }
                *(float2*)&hstate[r * HSTR + c2] = make_float2(h0, h1);
            }
            int off = ((r >> 4) * 8 + (c2 >> 5)) * 512 +
                      ((r & 15) + (((c2 & 31) >> 3) << 4)) * 8 + (c2 & 7);
            f16x2 hv2 = { (f16)h0, (f16)h1 };
            *(f16x2*)(frag + off) = hv2;
        }
    }

    int ln = t & 63, w = t >> 6;   // 8 waves

    // score mapping: t = i*16 + ch  (368 active)
    int sc_i  = t >> 4;
    int sc_ch = t & 15;
    int sc_hh = sc_ch >> 2;
    bool sc_act = (t < 368);
    int sb0 = SWZB(2 * sc_ch) * 8;
    int sb1 = SWZB(2 * sc_ch + 1) * 8;

    for (int layer = 0; layer < 3; ++layer) {
        if (layer > 0) {
            // convert hstate -> frag f16
            int c2 = (t & 127) * 2, rp = t >> 7;
            for (int r = rp; r < 48; r += 4) {
                float h0 = 0.f, h1 = 0.f;
                if (r < 46) {
                    float2 hv = *(const float2*)&hstate[r * HSTR + c2];
                    h0 = hv.x; h1 = hv.y;
                }
                int off = ((r >> 4) * 8 + (c2 >> 5)) * 512 +
                          ((r & 15) + (((c2 & 31) >> 3) << 4)) * 8 + (c2 & 7);
                f16x2 hv2 = { (f16)h0, (f16)h1 };
                *(f16x2*)(frag + off) = hv2;
            }
        }
        __syncthreads();   // frag ready (xs dead at layer 0)

        // one-time zero of alphaF (K-pad slots stay zero forever)
        if (layer == 0)
            *(f32x4*)(smem + ALPHA_OFF + t * 16) = (f32x4)0.f;

        // ---- GEMM: single-term f16; M=48(2 pad rows), 8 waves x 4 ntiles ----
        const f16* pB = Bf + (size_t)layer * 131072 + (size_t)(w * 4) * 4096 + ln * 8;
        const f16* lA = frag + ln * 8;

        f32x4 acc[3][4];
#pragma unroll
        for (int mt = 0; mt < 3; ++mt)
#pragma unroll
            for (int nt = 0; nt < 4; ++nt) acc[mt][nt] = (f32x4)0.0f;

        __builtin_amdgcn_s_setprio(1);
#pragma unroll
        for (int ks = 0; ks < 8; ++ks) {
            f16x8 a0 = *(const f16x8*)(lA + (0 * 8 + ks) * 512);
            f16x8 a1 = *(const f16x8*)(lA + (1 * 8 + ks) * 512);
            f16x8 a2 = *(const f16x8*)(lA + (2 * 8 + ks) * 512);
#pragma unroll
            for (int nt = 0; nt < 4; ++nt) {
                f16x8 b = *(const f16x8*)(pB + (nt * 8 + ks) * 512);
                acc[0][nt] = __builtin_amdgcn_mfma_f32_16x16x32_f16(a0, b, acc[0][nt], 0, 0, 0);
                acc[1][nt] = __builtin_amdgcn_mfma_f32_16x16x32_f16(a1, b, acc[1][nt], 0, 0, 0);
                acc[2][nt] = __builtin_amdgcn_mfma_f32_16x16x32_f16(a2, b, acc[2][nt], 0, 0, 0);
            }
        }
        __builtin_amdgcn_s_setprio(0);
        __syncthreads();   // frag dead; sl/sro writable

        // ---- per-frame attention ----
        for (int f = 0; f < 2; ++f) {
            // scatter acc -> swizzled f16 sl/sro
#pragma unroll
            for (int mt = 0; mt < 3; ++mt) {
                int rbase = mt * 16 + (ln >> 4) * 4;
#pragma unroll
                for (int nt = 0; nt < 4; ++nt) {
                    int col = w * 64 + nt * 16 + (ln & 15);
                    f16* dst = (col < 256) ? sl16 : sro16;
                    int cc = col & 255;
                    int sc = SWZC(cc);
#pragma unroll
                    for (int r2 = 0; r2 < 4; ++r2) {
                        int i = rbase + r2 - f * PP;
                        if (0 <= i && i < PP) dst[i * SLSTR + sc] = (f16)acc[mt][nt][r2];
                    }
                }
            }
            __syncthreads();

            // scores: packed leaky-relu + packed fma; write aF frag-layout
            if (sc_act) {
                const float* ap = att + layer * DD + sc_ch * 16;
                float4 af0 = *(const float4*)(ap);
                float4 af1 = *(const float4*)(ap + 4);
                float4 af2 = *(const float4*)(ap + 8);
                float4 af3 = *(const float4*)(ap + 12);
                f16x8 av0 = { (f16)af0.x, (f16)af0.y, (f16)af0.z, (f16)af0.w,
                              (f16)af1.x, (f16)af1.y, (f16)af1.z, (f16)af1.w };
                f16x8 av1 = { (f16)af2.x, (f16)af2.y, (f16)af2.z, (f16)af2.w,
                              (f16)af3.x, (f16)af3.y, (f16)af3.z, (f16)af3.w };
                const f16* srp = sro16 + sc_i * SLSTR;
                f16x8 rv0 = *(const f16x8*)(srp + sb0);
                f16x8 rv1 = *(const f16x8*)(srp + sb1);
                int wbase = ((sc_hh * 2 + (sc_i >> 4)) << 9) + ((sc_i & 15) << 3);
#pragma unroll 2
                for (int j = 0; j < PP; ++j) {
                    const f16* slp = sl16 + j * SLSTR;
                    f16x8 v0 = *(const f16x8*)(slp + sb0) + rv0;
                    f16x8 v1 = *(const f16x8*)(slp + sb1) + rv1;
                    v0 = __builtin_elementwise_max(v0, v0 * (f16)0.2f);
                    v1 = __builtin_elementwise_max(v1, v1 * (f16)0.2f);
                    f16x8 tot = av0 * v0;
                    tot += av1 * v1;
                    f16x4 t4 = __builtin_shufflevector(tot, tot, 0, 1, 2, 3) +
                               __builtin_shufflevector(tot, tot, 4, 5, 6, 7);
                    float p = (float)t4[0] + (float)t4[1] + (float)t4[2] + (float)t4[3];
                    p += __shfl_xor(p, 1, 64);
                    p += __shfl_xor(p, 2, 64);
                    if ((t & 3) == 0)
                        aF[wbase + ((j >> 3) << 7) + (j & 7)] =
                            (j == sc_i) ? (f16)(-60000.0f) : (f16)p;
                }
            }
            __syncthreads();

            // parallel softmax, 2-pass: max-reduce, then exp-write + sum; publish invZ
            if (t < 368) {
                int i = t >> 4, hh = (t >> 2) & 3, q = t & 3;
                int base = ((hh * 2 + (i >> 4)) << 9) + ((i & 15) << 3);
                float m = -1e30f;
                for (int j = q; j < PP; j += 4)
                    m = fmaxf(m, (float)aF[base + ((j >> 3) << 7) + (j & 7)]);
                m = fmaxf(m, __shfl_xor(m, 1, 64));
                m = fmaxf(m, __shfl_xor(m, 2, 64));
                float s = 0.f;
                for (int j = q; j < PP; j += 4) {
                    f16* p = aF + base + ((j >> 3) << 7) + (j & 7);
                    f16 e = (f16)__expf((float)*p - m);
                    *p = e;
                    s += (float)e;     // sum what the MFMA will actually sum
                }
                s += __shfl_xor(s, 1, 64);
                s += __shfl_xor(s, 2, 64);
                if (q == 0) invZ[i * 4 + hh] = 1.f / s;
            }
            __syncthreads();

            // aggregate via MFMA: wave w -> (head h, mtile mt); out = invZ * (e @ hl)
            {
                int h = w >> 1, mt = w & 1;
                f16x8 afrag = *(const f16x8*)(aF + ((h * 2 + mt) << 9) + ln * 8);
                int k0 = (ln >> 4) * 8;
                int cb = h * 64 + (ln & 15);
                __builtin_amdgcn_s_setprio(1);
#pragma unroll
                for (int nt = 0; nt < 4; ++nt) {
                    int c = cb + nt * 16;
                    int scn = SWZC(c);
                    f16x8 bfrag;
#pragma unroll
                    for (int e = 0; e < 8; ++e)
                        bfrag[e] = sl16[(k0 + e) * SLSTR + scn];
                    f32x4 a4 = __builtin_amdgcn_mfma_f32_16x16x32_f16(
                        afrag, bfrag, (f32x4)0.0f, 0, 0, 0);
#pragma unroll
                    for (int r2 = 0; r2 < 4; ++r2) {
                        int i = mt * 16 + (ln >> 4) * 4 + r2;
                        if (i < PP) {
                            int r = f * PP + i;
                            float res = a4[r2] * invZ[i * 4 + h] + hstate[r * HSTR + c];
                            hstate[r * HSTR + c] = (res > 0.f) ? res : (__expf(res) - 1.f);
                        }
                    }
                }
                __builtin_amdgcn_s_setprio(0);
            }
            __syncthreads();
        }
    }

    // ---- readout into LDS (aF region now dead) ----
    {
        int f = t >> 8, c = t & 255;
        float s = 0.f;
#pragma unroll
        for (int i = 0; i < PP; ++i) s += hstate[(f * PP + i) * HSTR + c];
        gv[f * 256 + c] = s * (1.0f / 23.0f);
    }
    __syncthreads();

    // ---- head phase A: t1 = relu(g@Wr1+br1), gtop = g@Ws1[:256]+bs1 ----
    {
        int gg = t >> 8, c = t & 255;
        const float* gp = gv + gg * 256;
        float a1 = 0.f, a2 = 0.f;
        for (int k = 0; k < DD; k += 2) {
            float g0 = gp[k], g1 = gp[k + 1];
            a1 = fmaf(g0, Wr1[k * DD + c], a1);
            a1 = fmaf(g1, Wr1[(k + 1) * DD + c], a1);
            a2 = fmaf(g0, Ws1[k * DD + c], a2);
            a2 = fmaf(g1, Ws1[(k + 1) * DD + c], a2);
        }
        t1s[gg * 256 + c] = fmaxf(a1 + br1[c], 0.f);
        gts[gg * 256 + c] = a2 + bs1[c];
    }
    __syncthreads();

    // ---- head phase B: logits ----
    if (t < 2 * CC) {
        int gg = t / CC, c = t - gg * CC;
        float acc = br2[c];
        const float* tp = t1s + gg * 256;
        for (int d = 0; d < DD; ++d) acc = fmaf(tp[d], Wr2[d * CC + c], acc);
        lgs[gg * CC + c] = acc;
    }
    __syncthreads();

    // ---- head phase C: recv softmax ----
    if (t < 2 * CC) {
        int gg = t / CC, c = t - gg * CC;
        const float* lp = lgs + gg * CC;
        float m = -1e30f;
        for (int cc = 0; cc < CC; ++cc) m = fmaxf(m, lp[cc]);
        float s = 0.f;
        for (int cc = 0; cc < CC; ++cc) s += __expf(lp[cc] - m);
        prb[gg * CC + c] = __expf(lp[c] - m) / s;
    }
    __syncthreads();

    // ---- head phase D: marginalized shot logit ----
    {
        int gg = t >> 8, c = t & 255;
        float gt = gts[gg * 256 + c];
        const float* pp = prb + gg * CC;
        float acc = 0.f;
#pragma unroll
        for (int cls = 0; cls < CC; ++cls)
            acc = fmaf(pp[cls], fmaxf(gt + EB[cls * DD + c], 0.f), acc);
        acc *= Ws2[c];
#pragma unroll
        for (int off = 32; off > 0; off >>= 1) acc += __shfl_down(acc, off, 64);
        if (ln == 0) red[w] = acc;
    }
    __syncthreads();
    if (t < 2)
        out[pair * 2 + t] = red[t * 4] + red[t * 4 + 1] + red[t * 4 + 2] +
                            red[t * 4 + 3] + bs2[0];
}

extern "C" void kernel_launch(void* const* d_in, const int* in_sizes, int n_in,
                              void* d_out, int out_size, void* d_ws, size_t ws_size,
                              hipStream_t stream)
{
    const float* x     = (const float*)d_in[0];
    const float* Win   = (const float*)d_in[3];
    const float* bin   = (const float*)d_in[4];
    const float* Wl    = (const float*)d_in[5];
    const float* Wr    = (const float*)d_in[6];
    const float* att   = (const float*)d_in[7];
    const float* Wr1   = (const float*)d_in[8];
    const float* br1   = (const float*)d_in[9];
    const float* Wr2   = (const float*)d_in[10];
    const float* br2   = (const float*)d_in[11];
    const float* Erecv = (const float*)d_in[12];
    const float* Ws1   = (const float*)d_in[13];
    const float* bs1   = (const float*)d_in[14];
    const float* Ws2   = (const float*)d_in[15];
    const float* bs2   = (const float*)d_in[16];
    float* out = (float*)d_out;

    f16* Bf   = (f16*)d_ws;                          // [3][32][4096] f16
    float* EB = (float*)(Bf + (size_t)3 * 131072);   // [CC][DD]

    k_prep<<<dim3(96 + CC), dim3(256), 0, stream>>>(Wl, Wr, Erecv, Ws1, Bf, EB);
    k_fused<<<dim3(NPAIR), dim3(512), 0, stream>>>(x, Win, bin, Bf, att,
        Wr1, br1, Wr2, br2, Ws1, bs1, Ws2, bs2, EB, out);
}